// Round 2
// baseline (2089.082 us; speedup 1.0000x reference)
//
#include <hip/hip_runtime.h>
#include <hip/hip_bf16.h>
#include <math.h>

typedef float floatx4 __attribute__((ext_vector_type(4)));

#define IN_DIM 128
#define OUT_DIM 64
// XCD-ownership of node d: 16 consecutive nodes share one owner in 0..7;
// blockIdx%8 round-robins XCDs so all RMWs/stores for a cursor/ssort line
// come from one XCD -> no cross-XCD line migration. (proven R9/R10)
#define OWNER(d) (((d) >> 4) & 7)
#define CHUNK 2048
#define CAP 32        // 128 B = 2 lines per node; P(Poisson(16)>32) ~ 2e-4
#define OVF_CAP 8192  // exact overflow path

// Role pattern, period 24 (lcm(3,8)): r = b%24.
//   r%3==0  -> GEMM block, g = b/3            (8 gemm slots / 24)
//   else    -> SCATTER block, x = b&7 = r&7   (16 scatter slots / 24,
//              each XCD value exactly twice). chunk = 2*(b/24) + j where
//              j=0 iff r is the FIRST scatter-residue for its x in the group.
// firsts per x = {8,1,2,11,4,5,14,7} -> bitmask bits {1,2,4,5,7,8,11,14}:
#define FIRSTMASK 0x49B6u

// ---------------------------------------------------------------------------
// Fused front kernel: VALU GEMM (z = h@W^T, s_src/s_dst) co-scheduled with the
// slotted edge scatter. Scatter waves are atomic-latency-bound (VALUBusy 5.5%
// measured standalone); gemm waves are VALU/LDS-bound. Interleaving roles 1:2
// in blockIdx lets each CU run ~2 gemm + ~4 scatter blocks concurrently.
// GEMM is K-split (two halves of 16 k4) so LDS = 24.75 KB -> 6 blocks/CU
// (24 waves/CU), matching the standalone scatter's ~70% occupancy.
// ---------------------------------------------------------------------------
__global__ __launch_bounds__(256, 6) void k_front(
    const float* __restrict__ h, const float* __restrict__ W,
    const float* __restrict__ a, __hip_bfloat16* __restrict__ z,
    float* __restrict__ s_src, float* __restrict__ s_dst, int nG,
    const int* __restrict__ src, const int* __restrict__ dst,
    int* __restrict__ cursor, int* __restrict__ ssort,
    int* __restrict__ ovfcnt, int2* __restrict__ ovf, int E, int nchunks)
{
    const int b = blockIdx.x;
    const int r = b % 24;
    const int tid = threadIdx.x;

    if (r % 3 == 0) {
        // ------------------------- GEMM role -------------------------
        __shared__ floatx4 sW[16 * 65];   // [k4l][c], pad 65 -> 16.25 KB
        __shared__ floatx4 sH[32 * 17];   // [n][k4l], pad 17 ->  8.5 KB
        const int g = b / 3;
        if (g >= nG) return;
        const int n0 = g * 32;
        const int wave = tid >> 6;
        const int c = tid & 63;

        floatx4 acc[8];
#pragma unroll
        for (int i = 0; i < 8; ++i) acc[i] = (floatx4){0.f, 0.f, 0.f, 0.f};

        const floatx4* W4 = (const floatx4*)W;
        const floatx4* H4 = (const floatx4*)h;

        for (int kh = 0; kh < 2; ++kh) {
            if (kh) __syncthreads();      // LDS reuse between halves
#pragma unroll
            for (int i = 0; i < 4; ++i) {
                int gg = tid + 256 * i;   // 0..1023
                int cc = gg >> 4, k4l = gg & 15;
                sW[k4l * 65 + cc] = W4[cc * 32 + kh * 16 + k4l];
            }
#pragma unroll
            for (int i = 0; i < 2; ++i) {
                int gg = tid + 256 * i;   // 0..511
                int n = gg >> 4, k4l = gg & 15;
                // nt: h lines are single-use; don't evict ssort/cursor lines
                sH[n * 17 + k4l] = __builtin_nontemporal_load(
                    &H4[(size_t)(n0 + n) * 32 + kh * 16 + k4l]);
            }
            __syncthreads();

            for (int k4l = 0; k4l < 16; ++k4l) {
                floatx4 w4 = sW[k4l * 65 + c];
#pragma unroll
                for (int i = 0; i < 8; ++i) {
                    floatx4 h4 = sH[(wave * 8 + i) * 17 + k4l];  // broadcast
                    acc[i].x += h4.x * w4.x;
                    acc[i].y += h4.y * w4.y;
                    acc[i].z += h4.z * w4.z;
                    acc[i].w += h4.w * w4.w;
                }
            }
        }

        const float a1 = a[c];
        const float a2 = a[OUT_DIM + c];
#pragma unroll
        for (int i = 0; i < 8; ++i) {
            int n = n0 + wave * 8 + i;
            float v = (acc[i].x + acc[i].y) + (acc[i].z + acc[i].w);
            z[(size_t)n * OUT_DIM + c] = __float2bfloat16(v);
            float ps = v * a1;
            float pd = v * a2;
#pragma unroll
            for (int off = 32; off >= 1; off >>= 1) {
                ps += __shfl_xor(ps, off);
                pd += __shfl_xor(pd, off);
            }
            if (c == 0) {
                s_src[n] = ps;
                s_dst[n] = pd;
            }
        }
    } else {
        // ------------------------ SCATTER role ------------------------
        const int x = r & 7;                       // == b&7 == physical XCD
        const int j = ((FIRSTMASK >> r) & 1u) ? 0 : 1;
        const int ch = (b / 24) * 2 + j;
        if (ch >= nchunks) return;
        const int e0 = ch * CHUNK;
#pragma unroll
        for (int i = 0; i < CHUNK / 256; ++i) {
            int e = e0 + i * 256 + tid;
            if (e < E) {
                int d = __builtin_nontemporal_load(&dst[e]);
                if (OWNER(d) == x) {
                    int s = __builtin_nontemporal_load(&src[e]);
                    int pos = atomicAdd(&cursor[d], 1);
                    if (pos < CAP) {
                        ssort[d * CAP + pos] = s;
                    } else {
                        int op = atomicAdd(ovfcnt, 1);
                        if (op < OVF_CAP) ovf[op] = make_int2(s, d);
                    }
                }
            }
        }
    }
}

// ---------------------------------------------------------------------------
// Fused per-node softmax + weighted gather + ELU. One wave/node, lane=col.
// Unshifted exp (validated R9/R10). 8-wide predicated gather unroll.
// nt on single-use streams (ssort read, out write) to keep z in L2.
// ---------------------------------------------------------------------------
__global__ __launch_bounds__(256) void k_node(
    const int* __restrict__ cursor, const int* __restrict__ ssort,
    const float* __restrict__ s_src, const float* __restrict__ s_dst,
    const int* __restrict__ ovfcnt, const int2* __restrict__ ovf,
    const __hip_bfloat16* __restrict__ z, float* __restrict__ out, int N)
{
    const int lane = threadIdx.x & 63;
    const int wave = threadIdx.x >> 6;
    const int n = blockIdx.x * 4 + wave;
    if (n >= N) return;

    const int deg_raw = cursor[n];
    if (deg_raw == 0) {                   // empty segment -> elu(0) = 0
        __builtin_nontemporal_store(0.f, &out[(size_t)n * OUT_DIM + lane]);
        return;
    }
    const int deg = min(deg_raw, CAP);
    const int base = n * CAP;
    const float sdn = s_dst[n];

    float sum = 0.f;                      // lane-partial softmax denom
    float acc = 0.f;                      // weighted feature accumulator
    {
        int kk = lane;                    // deg <= CAP=32 < 64: single pass
        int sv = 0;
        float ev = 0.f;
        if (kk < deg) {
            sv = __builtin_nontemporal_load(&ssort[base + kk]);
            float sc = s_src[sv] + sdn;
            sc = sc > 0.f ? sc : 0.01f * sc;   // leaky_relu
            ev = __expf(sc);
        }
        sum += ev;
        for (int j = 0; j < deg; j += 8) {
            float wgt[8], zv[8];
#pragma unroll
            for (int u = 0; u < 8; ++u) {
                int jj = j + u;
                bool ok = jj < deg;
                int s = __shfl(sv, ok ? jj : 0);
                float w = __shfl(ev, ok ? jj : 0);
                wgt[u] = ok ? w : 0.f;
                int sa = ok ? s : 0;
                zv[u] = __bfloat162float(z[(size_t)sa * OUT_DIM + lane]);
            }
#pragma unroll
            for (int u = 0; u < 8; ++u) acc += wgt[u] * zv[u];
        }
    }

    // exact overflow path (deg_raw > CAP): ~20 nodes, ovf list tiny
    if (deg_raw > CAP) {
        int oc = min(*ovfcnt, OVF_CAP);
        for (int i = 0; i < oc; ++i) {
            int2 p = ovf[i];
            if (p.y == n) {
                float sc = s_src[p.x] + sdn;
                sc = sc > 0.f ? sc : 0.01f * sc;
                float ev = __expf(sc);
                if (lane == 0) sum += ev;
                acc += ev * __bfloat162float(z[(size_t)p.x * OUT_DIM + lane]);
            }
        }
    }

#pragma unroll
    for (int off = 32; off >= 1; off >>= 1) sum += __shfl_xor(sum, off);

    float r = acc / sum;
    float o = r > 0.f ? r : expm1f(r);    // ELU, alpha=1
    __builtin_nontemporal_store(o, &out[(size_t)n * OUT_DIM + lane]);
}

// ---------------------------------------------------------------------------
extern "C" void kernel_launch(void* const* d_in, const int* in_sizes, int n_in,
                              void* d_out, int out_size, void* d_ws, size_t ws_size,
                              hipStream_t stream)
{
    (void)n_in; (void)out_size; (void)ws_size;

    const float* h  = (const float*)d_in[0];
    const int* src  = (const int*)d_in[1];
    const int* dst  = (const int*)d_in[2];
    const float* W  = (const float*)d_in[3];
    const float* a  = (const float*)d_in[4];
    const int N = in_sizes[0] / IN_DIM;
    const int E = in_sizes[1];
    float* out = (float*)d_out;

    char* wsp = (char*)d_ws;
    size_t off = 0;
    auto alloc = [&](size_t bytes) -> void* {
        void* p = wsp + off;
        off = (off + bytes + 255) & ~(size_t)255;
        return p;
    };
    __hip_bfloat16* z = (__hip_bfloat16*)alloc((size_t)N * OUT_DIM * 2);
    float* s_src = (float*)alloc((size_t)N * 4);
    float* s_dst = (float*)alloc((size_t)N * 4);
    int* cursor  = (int*)alloc((size_t)(N + 1) * 4);   // +1: ovfcnt tail
    int* ovfcnt  = cursor + N;
    int2* ovf    = (int2*)alloc((size_t)OVF_CAP * 8);
    int* ssort   = (int*)alloc((size_t)N * CAP * 4);   // 12.8 MB
    // total ~27 MB for N=1e5

    hipMemsetAsync(cursor, 0, (size_t)(N + 1) * 4, stream);

    const int nG = (N + 31) / 32;
    const int nchunks = (E + CHUNK - 1) / CHUNK;
    // groups of 24 blocks: 8 gemm slots + 2 scatter slots per XCD value
    const int tg = (nG + 7) / 8;
    const int ts = (nchunks + 1) / 2;
    const int T = tg > ts ? tg : ts;
    k_front<<<24 * T, 256, 0, stream>>>(h, W, a, z, s_src, s_dst, nG,
                                        src, dst, cursor, ssort, ovfcnt, ovf,
                                        E, nchunks);
    k_node<<<(N + 3) / 4, 256, 0, stream>>>(cursor, ssort, s_src, s_dst, ovfcnt, ovf, z, out, N);
}

// Round 3
// 298.016 us; speedup vs baseline: 7.0100x; 7.0100x over previous
//
#include <hip/hip_runtime.h>
#include <hip/hip_bf16.h>
#include <math.h>

typedef float floatx4 __attribute__((ext_vector_type(4)));

#define IN_DIM 128
#define OUT_DIM 64
// XCD-ownership of node d: 16 consecutive nodes share one owner in 0..7;
// blockIdx%8 round-robins XCDs so all RMWs/stores for a cursor/ssort line
// come from one XCD -> no cross-XCD line migration. (proven R9/R10)
#define OWNER(d) (((d) >> 4) & 7)
#define CHUNK 2048
#define CAP 32        // 128 B = 2 lines per node; P(Poisson(16)>32) ~ 2e-4
#define OVF_CAP 8192  // exact overflow path

// ---------------------------------------------------------------------------
// VALU GEMM: z = h @ W^T (fp32 exact), bf16 z out, fp32 s_src/s_dst out.
// (byte-identical to the verified 285 us baseline)
// ---------------------------------------------------------------------------
__global__ __launch_bounds__(256) void k_gemm(
    const float* __restrict__ h, const float* __restrict__ W,
    const float* __restrict__ a, __hip_bfloat16* __restrict__ z,
    float* __restrict__ s_src, float* __restrict__ s_dst, int N)
{
    __shared__ floatx4 sW[32 * 65];   // [k4][c], row stride 65 (pad)
    __shared__ floatx4 sH[32 * 33];   // [n][k4], row stride 33 (pad)

    const int tid = threadIdx.x;
    const int n0 = blockIdx.x * 32;

    const floatx4* W4 = (const floatx4*)W;
#pragma unroll
    for (int i = 0; i < 8; ++i) {
        int g = tid + 256 * i;            // 0..2047
        int c = g >> 5, k4 = g & 31;
        sW[k4 * 65 + c] = W4[g];
    }
    const floatx4* H4 = (const floatx4*)h;
#pragma unroll
    for (int i = 0; i < 4; ++i) {
        int g = tid + 256 * i;            // 0..1023
        int n = g >> 5, k4 = g & 31;
        sH[n * 33 + k4] = H4[(size_t)(n0 + n) * 32 + k4];
    }
    __syncthreads();

    const int wave = tid >> 6;
    const int c = tid & 63;

    floatx4 acc[8];
#pragma unroll
    for (int i = 0; i < 8; ++i) acc[i] = (floatx4){0.f, 0.f, 0.f, 0.f};

    for (int k4 = 0; k4 < 32; ++k4) {
        floatx4 w4 = sW[k4 * 65 + c];
#pragma unroll
        for (int i = 0; i < 8; ++i) {
            floatx4 h4 = sH[(wave * 8 + i) * 33 + k4];
            acc[i].x += h4.x * w4.x;
            acc[i].y += h4.y * w4.y;
            acc[i].z += h4.z * w4.z;
            acc[i].w += h4.w * w4.w;
        }
    }

    const float a1 = a[c];
    const float a2 = a[OUT_DIM + c];
#pragma unroll
    for (int i = 0; i < 8; ++i) {
        int n = n0 + wave * 8 + i;
        float v = (acc[i].x + acc[i].y) + (acc[i].z + acc[i].w);
        z[(size_t)n * OUT_DIM + c] = __float2bfloat16(v);
        float ps = v * a1;
        float pd = v * a2;
#pragma unroll
        for (int off = 32; off >= 1; off >>= 1) {
            ps += __shfl_xor(ps, off);
            pd += __shfl_xor(pd, off);
        }
        if (c == 0) {
            s_src[n] = ps;
            s_dst[n] = pd;
        }
    }
}

// ---------------------------------------------------------------------------
// Slotted scatter, MLP-restructured. Round-0 profile showed VGPR_Count=8:
// the compiler serialized the 8 iterations into dependent load->atomic->store
// chains (VALUBusy 5.5%, HBM 19% -- pure latency-bound). Batched phases force
// 8 independent loads, then 8 independent atomics, in flight per wave.
// nt loads: each dst/src line read once per XCD; don't evict ssort lines.
// ---------------------------------------------------------------------------
__global__ __launch_bounds__(256) void k_scatter(
    const int* __restrict__ src, const int* __restrict__ dst,
    int* __restrict__ cursor, int* __restrict__ ssort,
    int* __restrict__ ovfcnt, int2* __restrict__ ovf, int E)
{
    const int x = blockIdx.x & 7;
    const int c = blockIdx.x >> 3;
    const int e0 = c * CHUNK + threadIdx.x;

    int  dv[8];
    int  sv[8];
    int  pos[8];
    bool ok[8];

    // phase 1: all dst loads in flight
#pragma unroll
    for (int i = 0; i < 8; ++i) {
        int e = e0 + i * 256;
        bool inb = e < E;
        dv[i] = inb ? __builtin_nontemporal_load(&dst[e]) : 0;
        ok[i] = inb;
    }
    // phase 2: owner filter + src loads in flight
#pragma unroll
    for (int i = 0; i < 8; ++i) {
        ok[i] = ok[i] && (OWNER(dv[i]) == x);
        int e = e0 + i * 256;
        sv[i] = ok[i] ? __builtin_nontemporal_load(&src[e]) : 0;
    }
    // phase 3: all cursor atomics in flight
#pragma unroll
    for (int i = 0; i < 8; ++i) {
        if (ok[i]) pos[i] = atomicAdd(&cursor[dv[i]], 1);
    }
    // phase 4: slot stores (dependent on pos)
#pragma unroll
    for (int i = 0; i < 8; ++i) {
        if (ok[i]) {
            if (pos[i] < CAP) {
                ssort[dv[i] * CAP + pos[i]] = sv[i];
            } else {
                int op = atomicAdd(ovfcnt, 1);
                if (op < OVF_CAP) ovf[op] = make_int2(sv[i], dv[i]);
            }
        }
    }
}

// ---------------------------------------------------------------------------
// Fused per-node softmax + weighted gather + ELU. One wave/node, lane=col.
// Unshifted exp (validated R9/R10). 8-wide predicated gather unroll.
// nt on single-use streams (ssort read, out write) to keep z in L2.
// ---------------------------------------------------------------------------
__global__ __launch_bounds__(256) void k_node(
    const int* __restrict__ cursor, const int* __restrict__ ssort,
    const float* __restrict__ s_src, const float* __restrict__ s_dst,
    const int* __restrict__ ovfcnt, const int2* __restrict__ ovf,
    const __hip_bfloat16* __restrict__ z, float* __restrict__ out, int N)
{
    const int lane = threadIdx.x & 63;
    const int wave = threadIdx.x >> 6;
    const int n = blockIdx.x * 4 + wave;
    if (n >= N) return;

    const int deg_raw = cursor[n];
    if (deg_raw == 0) {                   // empty segment -> elu(0) = 0
        __builtin_nontemporal_store(0.f, &out[(size_t)n * OUT_DIM + lane]);
        return;
    }
    const int deg = min(deg_raw, CAP);
    const int base = n * CAP;
    const float sdn = s_dst[n];

    float sum = 0.f;                      // lane-partial softmax denom
    float acc = 0.f;                      // weighted feature accumulator
    {
        int kk = lane;                    // deg <= CAP=32 < 64: single pass
        int sv = 0;
        float ev = 0.f;
        if (kk < deg) {
            sv = __builtin_nontemporal_load(&ssort[base + kk]);
            float sc = s_src[sv] + sdn;
            sc = sc > 0.f ? sc : 0.01f * sc;   // leaky_relu
            ev = __expf(sc);
        }
        sum += ev;
        for (int j = 0; j < deg; j += 8) {
            float wgt[8], zv[8];
#pragma unroll
            for (int u = 0; u < 8; ++u) {
                int jj = j + u;
                bool ok = jj < deg;
                int s = __shfl(sv, ok ? jj : 0);
                float w = __shfl(ev, ok ? jj : 0);
                wgt[u] = ok ? w : 0.f;
                int sa = ok ? s : 0;
                zv[u] = __bfloat162float(z[(size_t)sa * OUT_DIM + lane]);
            }
#pragma unroll
            for (int u = 0; u < 8; ++u) acc += wgt[u] * zv[u];
        }
    }

    // exact overflow path (deg_raw > CAP): ~20 nodes, ovf list tiny
    if (deg_raw > CAP) {
        int oc = min(*ovfcnt, OVF_CAP);
        for (int i = 0; i < oc; ++i) {
            int2 p = ovf[i];
            if (p.y == n) {
                float sc = s_src[p.x] + sdn;
                sc = sc > 0.f ? sc : 0.01f * sc;
                float ev = __expf(sc);
                if (lane == 0) sum += ev;
                acc += ev * __bfloat162float(z[(size_t)p.x * OUT_DIM + lane]);
            }
        }
    }

#pragma unroll
    for (int off = 32; off >= 1; off >>= 1) sum += __shfl_xor(sum, off);

    float r = acc / sum;
    float o = r > 0.f ? r : expm1f(r);    // ELU, alpha=1
    __builtin_nontemporal_store(o, &out[(size_t)n * OUT_DIM + lane]);
}

// ---------------------------------------------------------------------------
extern "C" void kernel_launch(void* const* d_in, const int* in_sizes, int n_in,
                              void* d_out, int out_size, void* d_ws, size_t ws_size,
                              hipStream_t stream)
{
    (void)n_in; (void)out_size; (void)ws_size;

    const float* h  = (const float*)d_in[0];
    const int* src  = (const int*)d_in[1];
    const int* dst  = (const int*)d_in[2];
    const float* W  = (const float*)d_in[3];
    const float* a  = (const float*)d_in[4];
    const int N = in_sizes[0] / IN_DIM;
    const int E = in_sizes[1];
    float* out = (float*)d_out;

    char* wsp = (char*)d_ws;
    size_t off = 0;
    auto alloc = [&](size_t bytes) -> void* {
        void* p = wsp + off;
        off = (off + bytes + 255) & ~(size_t)255;
        return p;
    };
    __hip_bfloat16* z = (__hip_bfloat16*)alloc((size_t)N * OUT_DIM * 2);
    float* s_src = (float*)alloc((size_t)N * 4);
    float* s_dst = (float*)alloc((size_t)N * 4);
    int* cursor  = (int*)alloc((size_t)(N + 1) * 4);   // +1: ovfcnt tail
    int* ovfcnt  = cursor + N;
    int2* ovf    = (int2*)alloc((size_t)OVF_CAP * 8);
    int* ssort   = (int*)alloc((size_t)N * CAP * 4);   // 12.8 MB
    // total ~27 MB for N=1e5

    hipMemsetAsync(cursor, 0, (size_t)(N + 1) * 4, stream);

    const int nchunks = (E + CHUNK - 1) / CHUNK;
    k_gemm<<<(N + 31) / 32, 256, 0, stream>>>(h, W, a, z, s_src, s_dst, N);
    k_scatter<<<nchunks * 8, 256, 0, stream>>>(src, dst, cursor, ssort, ovfcnt, ovf, E);
    k_node<<<(N + 3) / 4, 256, 0, stream>>>(cursor, ssort, s_src, s_dst, ovfcnt, ovf, z, out, N);
}